// Round 7
// baseline (1510.454 us; speedup 1.0000x reference)
//
#include <hip/hip_runtime.h>
#include <math.h>

#define B 8
#define C 128
#define H 96
#define W 96
#define HW (H*W)         // 9216
#define EPS 1e-5f
#define LOSC 2048.f
#define ILOSC (1.f/2048.f)

typedef _Float16 half8 __attribute__((ext_vector_type(8)));
typedef float floatx4 __attribute__((ext_vector_type(4)));

// ---- NCHW (b,c,p) -> NHWC (b,p,c) tiled transpose --------------------------
__global__ __launch_bounds__(256) void nchw_to_nhwc(
    const float* __restrict__ in, float* __restrict__ outp)
{
    // grid: B * 288(px tiles) * 4(ch tiles)
    int blk = blockIdx.x;
    int b  = blk / (288 * 4);
    int r  = blk % (288 * 4);
    int p0 = (r / 4) * 32;
    int c0 = (r % 4) * 32;
    __shared__ float tile[32][33];
    int t  = threadIdx.x;
    int tp = t & 31, tr = t >> 5;   // 8 rows per pass
#pragma unroll
    for (int i = 0; i < 4; i++) {
        int c = c0 + tr + i * 8;
        tile[tr + i * 8][tp] = in[((size_t)b * C + c) * HW + p0 + tp];
    }
    __syncthreads();
#pragma unroll
    for (int i = 0; i < 4; i++) {
        int p = p0 + tr + i * 8;
        outp[((size_t)b * HW + p) * C + c0 + tp] = tile[tp][tr + i * 8];
    }
}

// ---- dcn weight -> split f16 (hi, lo*2048), layout wt[oc][kk*128+ic] -------
__global__ void wt_split(const float* __restrict__ w,
                         _Float16* __restrict__ hi, _Float16* __restrict__ lo) {
    int i = blockIdx.x * 256 + threadIdx.x;
    if (i >= C * C * 9) return;
    int oc = i / 1152, r = i % 1152, kk = r >> 7, ic = r & 127;
    float v = w[oc * 1152 + ic * 9 + kk];
    _Float16 h = (_Float16)v;
    hi[i] = h;
    lo[i] = (_Float16)((v - (float)h) * LOSC);
}

// ---- offset weight -> split f16, layout [32 (27+pad)][kk*128+ic] -----------
__global__ void offw_split(const float* __restrict__ w,
                           _Float16* __restrict__ hi, _Float16* __restrict__ lo) {
    int i = blockIdx.x * 256 + threadIdx.x;
    if (i >= 32 * 1152) return;
    int oc = i / 1152, r = i % 1152, kk = r >> 7, ic = r & 127;
    float v = (oc < 27) ? w[oc * 1152 + ic * 9 + kk] : 0.f;
    _Float16 h = (_Float16)v;
    hi[i] = h;
    lo[i] = (_Float16)((v - (float)h) * LOSC);
}

// ---- offset conv via split-f16 MFMA, NHWC input: C -> 27(pad 32) -----------
// block = 256 thr = 4 waves, 64 px; wave = 16 px x 32 oc (2 N-frags)
// XCD-swizzle: image b = blk&7 -> all of image b on one XCD (L2-resident).
__global__ __launch_bounds__(256) void off_mfma(
    const float* __restrict__ xt,
    const _Float16* __restrict__ wh, const _Float16* __restrict__ wl,
    const float* __restrict__ ob, float* __restrict__ omt)
{
    __shared__ int   s_oi[576];
    __shared__ float s_ow[576];

    int blk = blockIdx.x;
    int b  = blk & 7;               // XCD-aware: bijective, 1152 = 8*144
    int p0 = (blk >> 3) * 64;
    int t = threadIdx.x;

    for (int e = t; e < 576; e += 256) {
        int px = e & 63, kk = e >> 6;
        int p = p0 + px, h = p / W, w = p % W;
        int yy = h + kk / 3 - 1, xx = w + kk % 3 - 1;
        bool v = (yy >= 0) & (yy < H) & (xx >= 0) & (xx < W);
        int yc = min(max(yy, 0), H - 1), xc = min(max(xx, 0), W - 1);
        s_oi[px * 9 + kk] = yc * W + xc;
        s_ow[px * 9 + kk] = v ? 1.f : 0.f;
    }
    __syncthreads();

    int wave = t >> 6, lane = t & 63;
    int row = lane & 15, g = lane >> 4;
    int pxl = wave * 16 + row;
    const float* xb = xt + (size_t)b * HW * C;

    floatx4 acch[2], accl[2];
#pragma unroll
    for (int nf = 0; nf < 2; nf++) {
        acch[nf] = (floatx4){0.f, 0.f, 0.f, 0.f};
        accl[nf] = (floatx4){0.f, 0.f, 0.f, 0.f};
    }

    for (int kk = 0; kk < 9; kk++) {
        int   iv = s_oi[pxl * 9 + kk];
        float wv = s_ow[pxl * 9 + kk];
        const float* cp = xb + (size_t)iv * C;
#pragma unroll
        for (int icq = 0; icq < 4; icq++) {
            int icb = icq * 32 + g * 8;
            floatx4 pa = *(const floatx4*)(cp + icb);
            floatx4 pb = *(const floatx4*)(cp + icb + 4);
            half8 ah, al;
#pragma unroll
            for (int j = 0; j < 4; j++) {
                float v  = wv * pa[j];
                float v2 = wv * pb[j];
                _Float16 h1 = (_Float16)v;
                ah[j] = h1; al[j] = (_Float16)((v - (float)h1) * LOSC);
                _Float16 h2 = (_Float16)v2;
                ah[j + 4] = h2; al[j + 4] = (_Float16)((v2 - (float)h2) * LOSC);
            }
            int kb = kk * 128 + icq * 32 + g * 8;
#pragma unroll
            for (int nf = 0; nf < 2; nf++) {
                size_t wo = (size_t)(nf * 16 + row) * 1152 + kb;
                half8 bh = *(const half8*)(wh + wo);
                half8 bl = *(const half8*)(wl + wo);
                acch[nf] = __builtin_amdgcn_mfma_f32_16x16x32_f16(ah, bh, acch[nf], 0, 0, 0);
                accl[nf] = __builtin_amdgcn_mfma_f32_16x16x32_f16(al, bh, accl[nf], 0, 0, 0);
                accl[nf] = __builtin_amdgcn_mfma_f32_16x16x32_f16(ah, bl, accl[nf], 0, 0, 0);
            }
        }
    }

    int pxo = p0 + wave * 16 + g * 4;
#pragma unroll
    for (int nf = 0; nf < 2; nf++) {
        int oc = nf * 16 + row;
        if (oc < 27) {
            float bi = ob[oc];
#pragma unroll
            for (int r = 0; r < 4; r++)
                omt[((size_t)b * HW + pxo + r) * 32 + oc] =
                    acch[nf][r] + accl[nf][r] * ILOSC + bi;
        }
    }
}

// ---- DCNv2 + bias + BN + ReLU via split-f16 MFMA, NHWC input ---------------
// block = 256 thr = 4 waves, 64 px; wave = 16 px x 128 oc (8 N-frags)
template <bool NHWC_OUT>
__global__ __launch_bounds__(256) void dcn_mfma(
    const float* __restrict__ xt,      // (b, p, 128)
    const float* __restrict__ omt,     // (b, p, 32)
    const _Float16* __restrict__ wh, const _Float16* __restrict__ wl,
    const float* __restrict__ bias,
    const float* __restrict__ bn_g, const float* __restrict__ bn_b,
    const float* __restrict__ bn_m, const float* __restrict__ bn_v,
    float* __restrict__ out)
{
    __shared__ int4   s_idx[576];   // [px*9+kk] 4 corners
    __shared__ float4 s_wgt[576];

    int blk = blockIdx.x;
    int b  = blk & 7;               // XCD-aware: bijective, 1152 = 8*144
    int p0 = (blk >> 3) * 64;
    int t = threadIdx.x;

    int*   si = (int*)s_idx;
    float* sw = (float*)s_wgt;
    for (int e = t; e < 576; e += 256) {
        int px = e & 63, kk = e >> 6;
        int p = p0 + px, h = p / W, w = p % W;
        const float* obp = omt + ((size_t)b * HW + p) * 32;
        float dy = obp[2 * kk];
        float dx = obp[2 * kk + 1];
        float mk = obp[18 + kk];
        float m  = 1.f / (1.f + __expf(-mk));
        float py  = (float)h - 1.f + (float)(kk / 3) + dy;
        float pxx = (float)w - 1.f + (float)(kk % 3) + dx;
        float y0f = floorf(py), x0f = floorf(pxx);
        float wy1 = py - y0f, wx1 = pxx - x0f;
        int y0 = (int)y0f, x0 = (int)x0f;
#pragma unroll
        for (int j = 0; j < 4; j++) {
            int yy = y0 + (j >> 1), xx = x0 + (j & 1);
            bool v = (yy >= 0) & (yy < H) & (xx >= 0) & (xx < W);
            float wg = ((j >> 1) ? wy1 : 1.f - wy1) * ((j & 1) ? wx1 : 1.f - wx1) * m;
            int yc = min(max(yy, 0), H - 1), xc = min(max(xx, 0), W - 1);
            si[(px * 9 + kk) * 4 + j] = yc * W + xc;
            sw[(px * 9 + kk) * 4 + j] = v ? wg : 0.f;
        }
    }
    __syncthreads();

    int wave = t >> 6, lane = t & 63;
    int row = lane & 15, g = lane >> 4;
    int pxl = wave * 16 + row;
    const float* xb = xt + (size_t)b * HW * C;

    floatx4 acch[8], accl[8];
#pragma unroll
    for (int nf = 0; nf < 8; nf++) {
        acch[nf] = (floatx4){0.f, 0.f, 0.f, 0.f};
        accl[nf] = (floatx4){0.f, 0.f, 0.f, 0.f};
    }

    for (int kk = 0; kk < 9; kk++) {
        int4   iv = s_idx[pxl * 9 + kk];
        float4 wv = s_wgt[pxl * 9 + kk];
        const float* cp0 = xb + (size_t)iv.x * C;
        const float* cp1 = xb + (size_t)iv.y * C;
        const float* cp2 = xb + (size_t)iv.z * C;
        const float* cp3 = xb + (size_t)iv.w * C;
        float wx = wv.x, wy = wv.y, wz = wv.z, ww = wv.w;
#pragma unroll
        for (int icq = 0; icq < 4; icq++) {
            int icb = icq * 32 + g * 8;
            floatx4 p0a = *(const floatx4*)(cp0 + icb);
            floatx4 p0b = *(const floatx4*)(cp0 + icb + 4);
            floatx4 p1a = *(const floatx4*)(cp1 + icb);
            floatx4 p1b = *(const floatx4*)(cp1 + icb + 4);
            floatx4 p2a = *(const floatx4*)(cp2 + icb);
            floatx4 p2b = *(const floatx4*)(cp2 + icb + 4);
            floatx4 p3a = *(const floatx4*)(cp3 + icb);
            floatx4 p3b = *(const floatx4*)(cp3 + icb + 4);
            half8 ah, al;
#pragma unroll
            for (int j = 0; j < 4; j++) {
                float v  = wx * p0a[j] + wy * p1a[j] + wz * p2a[j] + ww * p3a[j];
                float v2 = wx * p0b[j] + wy * p1b[j] + wz * p2b[j] + ww * p3b[j];
                _Float16 h1 = (_Float16)v;
                ah[j] = h1; al[j] = (_Float16)((v - (float)h1) * LOSC);
                _Float16 h2 = (_Float16)v2;
                ah[j + 4] = h2; al[j + 4] = (_Float16)((v2 - (float)h2) * LOSC);
            }
            int kb = kk * 128 + icq * 32 + g * 8;
#pragma unroll
            for (int nf = 0; nf < 8; nf++) {
                size_t wo = (size_t)(nf * 16 + row) * 1152 + kb;
                half8 bh = *(const half8*)(wh + wo);
                half8 bl = *(const half8*)(wl + wo);
                acch[nf] = __builtin_amdgcn_mfma_f32_16x16x32_f16(ah, bh, acch[nf], 0, 0, 0);
                accl[nf] = __builtin_amdgcn_mfma_f32_16x16x32_f16(al, bh, accl[nf], 0, 0, 0);
                accl[nf] = __builtin_amdgcn_mfma_f32_16x16x32_f16(ah, bl, accl[nf], 0, 0, 0);
            }
        }
    }

    int pxo = p0 + wave * 16 + g * 4;
#pragma unroll
    for (int nf = 0; nf < 8; nf++) {
        int oc = nf * 16 + row;
        float sc = bn_g[oc] * rsqrtf(bn_v[oc] + EPS);
        float sh = bn_b[oc] - bn_m[oc] * sc;
        float bi = bias[oc];
#pragma unroll
        for (int r = 0; r < 4; r++) {
            float v = acch[nf][r] + accl[nf][r] * ILOSC + bi;
            v = fmaxf(v * sc + sh, 0.f);
            if (NHWC_OUT)
                out[((size_t)b * HW + pxo + r) * C + oc] = v;
            else
                out[((size_t)b * C + oc) * HW + pxo + r] = v;
        }
    }
}

// ---------------- per-(b,c) max & mean reduce (NCHW input) -----------------
__global__ __launch_bounds__(256) void reduce_bc(
    const float* __restrict__ o2, float* __restrict__ mx, float* __restrict__ av)
{
    int bc = blockIdx.x;
    const float* p = o2 + (size_t)bc * HW;
    int t = threadIdx.x;
    float m = -INFINITY, s = 0.f;
    for (int i = t; i < HW; i += 256) {
        float v = p[i];
        m = fmaxf(m, v);
        s += v;
    }
    __shared__ float sm[256], ss[256];
    sm[t] = m; ss[t] = s;
    __syncthreads();
    for (int off = 128; off > 0; off >>= 1) {
        if (t < off) {
            sm[t] = fmaxf(sm[t], sm[t + off]);
            ss[t] += ss[t + off];
        }
        __syncthreads();
    }
    if (t == 0) {
        mx[bc] = sm[0];
        av[bc] = ss[0] / (float)HW;
    }
}

// ---------------- channel attention MLP + sigmoid --------------------------
__global__ __launch_bounds__(128) void cam_gate(
    const float* __restrict__ mx, const float* __restrict__ av,
    const float* __restrict__ w1, const float* __restrict__ w2,
    float* __restrict__ ch)
{
    int b = blockIdx.x;
    int t = threadIdx.x;
    __shared__ float smx[C], sav[C], h1[32], h2[32];
    smx[t] = mx[b * C + t];
    sav[t] = av[b * C + t];
    __syncthreads();
    if (t < 32) {
        float a = 0.f, c = 0.f;
        for (int i = 0; i < C; i++) {
            float w = w1[t * C + i];
            a = fmaf(smx[i], w, a);
            c = fmaf(sav[i], w, c);
        }
        h1[t] = fmaxf(a, 0.f);
        h2[t] = fmaxf(c, 0.f);
    }
    __syncthreads();
    float a = 0.f;
#pragma unroll
    for (int j = 0; j < 32; j++) a += (h1[j] + h2[j]) * w2[t * 32 + j];
    ch[b * C + t] = 1.f / (1.f + __expf(-a));
}

// ---------------- final gating scale (in-place on out) ---------------------
__global__ __launch_bounds__(256) void scale_out(
    float* __restrict__ o2, const float* __restrict__ ch)
{
    int e = blockIdx.x * 256 + threadIdx.x;   // float4 index
    if (e >= B * C * HW / 4) return;
    int bc = e / (HW / 4);
    float g = ch[bc];
    float4 v = reinterpret_cast<const float4*>(o2)[e];
    v.x *= g; v.y *= g; v.z *= g; v.w *= g;
    reinterpret_cast<float4*>(o2)[e] = v;
}

extern "C" void kernel_launch(void* const* d_in, const int* in_sizes, int n_in,
                              void* d_out, int out_size, void* d_ws, size_t ws_size,
                              hipStream_t stream) {
    const float* x      = (const float*)d_in[0];
    const float* off_w1 = (const float*)d_in[1];
    const float* off_b1 = (const float*)d_in[2];
    const float* dcn_w1 = (const float*)d_in[3];
    const float* dcn_b1 = (const float*)d_in[4];
    const float* bn_g1  = (const float*)d_in[5];
    const float* bn_b1  = (const float*)d_in[6];
    const float* bn_m1  = (const float*)d_in[7];
    const float* bn_v1  = (const float*)d_in[8];
    const float* off_w2 = (const float*)d_in[9];
    const float* off_b2 = (const float*)d_in[10];
    const float* dcn_w2 = (const float*)d_in[11];
    const float* dcn_b2 = (const float*)d_in[12];
    const float* bn_g2  = (const float*)d_in[13];
    const float* bn_b2  = (const float*)d_in[14];
    const float* bn_m2  = (const float*)d_in[15];
    const float* bn_v2  = (const float*)d_in[16];
    const float* cam_w1 = (const float*)d_in[17];
    const float* cam_w2 = (const float*)d_in[18];
    float* out = (float*)d_out;

    float* ws  = (float*)d_ws;
    float* xt  = ws;                      // 9,437,184 f32 (NHWC x)
    float* o1t = xt + 9437184;            // 9,437,184 f32 (NHWC o1)
    float* omt = o1t + 9437184;           // 8*9216*32 = 2,359,296 f32
    _Float16* wt1h = (_Float16*)(omt + 2359296);  // 147,456 f16 each
    _Float16* wt1l = wt1h + 147456;
    _Float16* wt2h = wt1l + 147456;
    _Float16* wt2l = wt2h + 147456;
    _Float16* ow1h = wt2l + 147456;               // 36,864 f16 each
    _Float16* ow1l = ow1h + 36864;
    _Float16* ow2h = ow1l + 36864;
    _Float16* ow2l = ow2h + 36864;
    float* mxv = (float*)(ow2l + 36864);
    float* avv = mxv + 1024;
    float* chv = avv + 1024;

    nchw_to_nhwc<<<B * 288 * 4, 256, 0, stream>>>(x, xt);
    wt_split <<<576, 256, 0, stream>>>(dcn_w1, wt1h, wt1l);
    wt_split <<<576, 256, 0, stream>>>(dcn_w2, wt2h, wt2l);
    offw_split<<<144, 256, 0, stream>>>(off_w1, ow1h, ow1l);
    offw_split<<<144, 256, 0, stream>>>(off_w2, ow2h, ow2l);

    // stage 1: x(NHWC) -> o1t(NHWC)
    off_mfma<<<1152, 256, 0, stream>>>(xt, ow1h, ow1l, off_b1, omt);
    dcn_mfma<true><<<1152, 256, 0, stream>>>(xt, omt, wt1h, wt1l, dcn_b1,
                                             bn_g1, bn_b1, bn_m1, bn_v1, o1t);
    // stage 2: o1t(NHWC) -> out(NCHW, in d_out)
    off_mfma<<<1152, 256, 0, stream>>>(o1t, ow2h, ow2l, off_b2, omt);
    dcn_mfma<false><<<1152, 256, 0, stream>>>(o1t, omt, wt2h, wt2l, dcn_b2,
                                              bn_g2, bn_b2, bn_m2, bn_v2, out);

    // channel attention on out (NCHW), gate in-place
    reduce_bc<<<B * C, 256, 0, stream>>>(out, mxv, avv);
    cam_gate <<<B, 128, 0, stream>>>(mxv, avv, cam_w1, cam_w2, chv);
    scale_out<<<(B * C * HW / 4 + 255) / 256, 256, 0, stream>>>(out, chv);
}

// Round 10
// 833.418 us; speedup vs baseline: 1.8124x; 1.8124x over previous
//
#include <hip/hip_runtime.h>
#include <math.h>

#define B 8
#define C 128
#define H 96
#define W 96
#define HW (H*W)         // 9216
#define EPS 1e-5f
#define LOSC 2048.f
#define ILOSC (1.f/2048.f)

typedef _Float16 half8 __attribute__((ext_vector_type(8)));
typedef float floatx4 __attribute__((ext_vector_type(4)));

// ---- NCHW (b,c,p) -> NHWC (b,p,c) tiled transpose --------------------------
__global__ __launch_bounds__(256) void nchw_to_nhwc(
    const float* __restrict__ in, float* __restrict__ outp)
{
    int blk = blockIdx.x;
    int b  = blk / (288 * 4);
    int r  = blk % (288 * 4);
    int p0 = (r / 4) * 32;
    int c0 = (r % 4) * 32;
    __shared__ float tile[32][33];
    int t  = threadIdx.x;
    int tp = t & 31, tr = t >> 5;
#pragma unroll
    for (int i = 0; i < 4; i++) {
        int c = c0 + tr + i * 8;
        tile[tr + i * 8][tp] = in[((size_t)b * C + c) * HW + p0 + tp];
    }
    __syncthreads();
#pragma unroll
    for (int i = 0; i < 4; i++) {
        int p = p0 + tr + i * 8;
        outp[((size_t)b * HW + p) * C + c0 + tp] = tile[tp][tr + i * 8];
    }
}

// ---- dcn weight -> split f16 (hi, lo*2048), layout wt[oc][kk*128+ic] -------
// (R7's exact proven transform)
__global__ void wt_split(const float* __restrict__ w,
                         _Float16* __restrict__ hi, _Float16* __restrict__ lo) {
    int i = blockIdx.x * 256 + threadIdx.x;
    if (i >= C * C * 9) return;
    int oc = i / 1152, r = i % 1152, kk = r >> 7, ic = r & 127;
    float v = w[oc * 1152 + ic * 9 + kk];
    _Float16 h = (_Float16)v;
    hi[i] = h;
    lo[i] = (_Float16)((v - (float)h) * LOSC);
}

// ---- offset weight -> split f16, layout [32 (27+pad)][kk*128+ic] -----------
__global__ void offw_split(const float* __restrict__ w,
                           _Float16* __restrict__ hi, _Float16* __restrict__ lo) {
    int i = blockIdx.x * 256 + threadIdx.x;
    if (i >= 32 * 1152) return;
    int oc = i / 1152, r = i % 1152, kk = r >> 7, ic = r & 127;
    float v = (oc < 27) ? w[oc * 1152 + ic * 9 + kk] : 0.f;
    _Float16 h = (_Float16)v;
    hi[i] = h;
    lo[i] = (_Float16)((v - (float)h) * LOSC);
}

// ---- offset conv via split-f16 MFMA, NHWC input: C -> 27(pad 32) -----------
// R7 structure; ONLY change: B-fragments staged through LDS (swizzled half8).
__global__ __launch_bounds__(256) void off_mfma(
    const float* __restrict__ xt,
    const _Float16* __restrict__ wh, const _Float16* __restrict__ wl,
    const float* __restrict__ ob, float* __restrict__ omt)
{
    __shared__ int   s_oi[576];
    __shared__ float s_ow[576];
    __shared__ half8 sWh[256];   // [oc 0..31][grp 0..7], grp swizzled ^(oc&7)
    __shared__ half8 sWl[256];

    int blk = blockIdx.x;
    int b  = blk & 7;                 // XCD-aware, bijective (1152 = 8*144)
    int p0 = (blk >> 3) * 64;
    int t = threadIdx.x;

    for (int e = t; e < 576; e += 256) {
        int px = e & 63, kk = e >> 6;
        int p = p0 + px, h = p / W, w = p % W;
        int yy = h + kk / 3 - 1, xx = w + kk % 3 - 1;
        bool v = (yy >= 0) & (yy < H) & (xx >= 0) & (xx < W);
        int yc = min(max(yy, 0), H - 1), xc = min(max(xx, 0), W - 1);
        s_oi[px * 9 + kk] = yc * W + xc;
        s_ow[px * 9 + kk] = v ? 1.f : 0.f;
    }
    __syncthreads();

    int wave = t >> 6, lane = t & 63;
    int row = lane & 15, g = lane >> 4;
    int pxl = wave * 16 + row;
    int soc  = t >> 3;                // staging oc 0..31
    int sgrp = t & 7;                 // staging 8-ch group 0..7
    const float* xb = xt + (size_t)b * HW * C;

    floatx4 acch[2], accl[2];
#pragma unroll
    for (int nf = 0; nf < 2; nf++) {
        acch[nf] = (floatx4){0.f, 0.f, 0.f, 0.f};
        accl[nf] = (floatx4){0.f, 0.f, 0.f, 0.f};
    }

    for (int kk = 0; kk < 9; kk++) {
        int   iv = s_oi[pxl * 9 + kk];
        float wv = s_ow[pxl * 9 + kk];
        const float* cp = xb + (size_t)iv * C;
        for (int icqp = 0; icqp < 2; icqp++) {
            // stage W chunk: 32 oc x 64 ic, coalesced global, swizzled ds_write
            {
                size_t go = (size_t)soc * 1152 + kk * 128 + icqp * 64 + sgrp * 8;
                int dst = soc * 8 + (sgrp ^ (soc & 7));
                sWh[dst] = *(const half8*)(wh + go);
                sWl[dst] = *(const half8*)(wl + go);
            }
            // A gather to regs (R7's proven per-lane path)
            half8 ah[2], al[2];
#pragma unroll
            for (int icq2 = 0; icq2 < 2; icq2++) {
                int icb = icqp * 64 + icq2 * 32 + g * 8;
                floatx4 pa = *(const floatx4*)(cp + icb);
                floatx4 pb = *(const floatx4*)(cp + icb + 4);
#pragma unroll
                for (int j = 0; j < 4; j++) {
                    float v  = wv * pa[j];
                    float v2 = wv * pb[j];
                    _Float16 h1 = (_Float16)v;
                    ah[icq2][j] = h1; al[icq2][j] = (_Float16)((v - (float)h1) * LOSC);
                    _Float16 h2 = (_Float16)v2;
                    ah[icq2][j + 4] = h2; al[icq2][j + 4] = (_Float16)((v2 - (float)h2) * LOSC);
                }
            }
            __syncthreads();
#pragma unroll
            for (int icq2 = 0; icq2 < 2; icq2++) {
#pragma unroll
                for (int nf = 0; nf < 2; nf++) {
                    int oc = nf * 16 + row;
                    int wi = oc * 8 + ((icq2 * 4 + g) ^ (oc & 7));
                    half8 bh = sWh[wi];
                    half8 bl = sWl[wi];
                    acch[nf] = __builtin_amdgcn_mfma_f32_16x16x32_f16(ah[icq2], bh, acch[nf], 0, 0, 0);
                    accl[nf] = __builtin_amdgcn_mfma_f32_16x16x32_f16(al[icq2], bh, accl[nf], 0, 0, 0);
                    accl[nf] = __builtin_amdgcn_mfma_f32_16x16x32_f16(ah[icq2], bl, accl[nf], 0, 0, 0);
                }
            }
            __syncthreads();
        }
    }

    int pxo = p0 + wave * 16 + g * 4;
#pragma unroll
    for (int nf = 0; nf < 2; nf++) {
        int oc = nf * 16 + row;
        if (oc < 27) {
            float bi = ob[oc];
#pragma unroll
            for (int r = 0; r < 4; r++)
                omt[((size_t)b * HW + pxo + r) * 32 + oc] =
                    acch[nf][r] + accl[nf][r] * ILOSC + bi;
        }
    }
}

// ---- DCNv2 + bias + BN + ReLU via split-f16 MFMA, NHWC input ---------------
// R7 structure; ONLY change: B-fragments staged through LDS (swizzled half8).
template <bool NHWC_OUT>
__global__ __launch_bounds__(256) void dcn_mfma(
    const float* __restrict__ xt,      // (b, p, 128)
    const float* __restrict__ omt,     // (b, p, 32)
    const _Float16* __restrict__ wh, const _Float16* __restrict__ wl,
    const float* __restrict__ bias,
    const float* __restrict__ bn_g, const float* __restrict__ bn_b,
    const float* __restrict__ bn_m, const float* __restrict__ bn_v,
    float* __restrict__ out)
{
    __shared__ int4   s_idx[576];
    __shared__ float4 s_wgt[576];
    __shared__ half8  sWh[1024];   // [oc 0..127][grp 0..7], grp swizzled ^(oc&7)
    __shared__ half8  sWl[1024];

    int blk = blockIdx.x;
    int b  = blk & 7;                 // XCD-aware, bijective
    int p0 = (blk >> 3) * 64;
    int t = threadIdx.x;

    int*   si = (int*)s_idx;
    float* sw = (float*)s_wgt;
    for (int e = t; e < 576; e += 256) {
        int px = e & 63, kk = e >> 6;
        int p = p0 + px, h = p / W, w = p % W;
        const float* obp = omt + ((size_t)b * HW + p) * 32;
        float dy = obp[2 * kk];
        float dx = obp[2 * kk + 1];
        float mk = obp[18 + kk];
        float m  = 1.f / (1.f + __expf(-mk));
        float py  = (float)h - 1.f + (float)(kk / 3) + dy;
        float pxx = (float)w - 1.f + (float)(kk % 3) + dx;
        float y0f = floorf(py), x0f = floorf(pxx);
        float wy1 = py - y0f, wx1 = pxx - x0f;
        int y0 = (int)y0f, x0 = (int)x0f;
#pragma unroll
        for (int j = 0; j < 4; j++) {
            int yy = y0 + (j >> 1), xx = x0 + (j & 1);
            bool v = (yy >= 0) & (yy < H) & (xx >= 0) & (xx < W);
            float wg = ((j >> 1) ? wy1 : 1.f - wy1) * ((j & 1) ? wx1 : 1.f - wx1) * m;
            int yc = min(max(yy, 0), H - 1), xc = min(max(xx, 0), W - 1);
            si[(px * 9 + kk) * 4 + j] = yc * W + xc;
            sw[(px * 9 + kk) * 4 + j] = v ? wg : 0.f;
        }
    }
    __syncthreads();

    int wave = t >> 6, lane = t & 63;
    int row = lane & 15, g = lane >> 4;
    int pxl = wave * 16 + row;
    int soc  = t >> 3;                // staging oc base 0..31 (4 passes -> 128)
    int sgrp = t & 7;
    const float* xb = xt + (size_t)b * HW * C;

    floatx4 acch[8], accl[8];
#pragma unroll
    for (int nf = 0; nf < 8; nf++) {
        acch[nf] = (floatx4){0.f, 0.f, 0.f, 0.f};
        accl[nf] = (floatx4){0.f, 0.f, 0.f, 0.f};
    }

    for (int kk = 0; kk < 9; kk++) {
        int4   iv = s_idx[pxl * 9 + kk];
        float4 wv = s_wgt[pxl * 9 + kk];
        const float* cp0 = xb + (size_t)iv.x * C;
        const float* cp1 = xb + (size_t)iv.y * C;
        const float* cp2 = xb + (size_t)iv.z * C;
        const float* cp3 = xb + (size_t)iv.w * C;
        float wx = wv.x, wy = wv.y, wz = wv.z, ww = wv.w;
        for (int icqp = 0; icqp < 2; icqp++) {
            // stage W chunk: 128 oc x 64 ic, coalesced global, swizzled ds_write
#pragma unroll
            for (int p = 0; p < 4; p++) {
                int oc = p * 32 + soc;
                size_t go = (size_t)oc * 1152 + kk * 128 + icqp * 64 + sgrp * 8;
                int dst = oc * 8 + (sgrp ^ (oc & 7));
                sWh[dst] = *(const half8*)(wh + go);
                sWl[dst] = *(const half8*)(wl + go);
            }
            // A gather to regs (R7's proven per-lane path)
            half8 ah[2], al[2];
#pragma unroll
            for (int icq2 = 0; icq2 < 2; icq2++) {
                int icb = icqp * 64 + icq2 * 32 + g * 8;
                floatx4 p0a = *(const floatx4*)(cp0 + icb);
                floatx4 p0b = *(const floatx4*)(cp0 + icb + 4);
                floatx4 p1a = *(const floatx4*)(cp1 + icb);
                floatx4 p1b = *(const floatx4*)(cp1 + icb + 4);
                floatx4 p2a = *(const floatx4*)(cp2 + icb);
                floatx4 p2b = *(const floatx4*)(cp2 + icb + 4);
                floatx4 p3a = *(const floatx4*)(cp3 + icb);
                floatx4 p3b = *(const floatx4*)(cp3 + icb + 4);
#pragma unroll
                for (int j = 0; j < 4; j++) {
                    float v  = wx * p0a[j] + wy * p1a[j] + wz * p2a[j] + ww * p3a[j];
                    float v2 = wx * p0b[j] + wy * p1b[j] + wz * p2b[j] + ww * p3b[j];
                    _Float16 h1 = (_Float16)v;
                    ah[icq2][j] = h1; al[icq2][j] = (_Float16)((v - (float)h1) * LOSC);
                    _Float16 h2 = (_Float16)v2;
                    ah[icq2][j + 4] = h2; al[icq2][j + 4] = (_Float16)((v2 - (float)h2) * LOSC);
                }
            }
            __syncthreads();
#pragma unroll
            for (int icq2 = 0; icq2 < 2; icq2++) {
#pragma unroll
                for (int nf = 0; nf < 8; nf++) {
                    int oc = nf * 16 + row;
                    int wi = oc * 8 + ((icq2 * 4 + g) ^ (oc & 7));
                    half8 bh = sWh[wi];
                    half8 bl = sWl[wi];
                    acch[nf] = __builtin_amdgcn_mfma_f32_16x16x32_f16(ah[icq2], bh, acch[nf], 0, 0, 0);
                    accl[nf] = __builtin_amdgcn_mfma_f32_16x16x32_f16(al[icq2], bh, accl[nf], 0, 0, 0);
                    accl[nf] = __builtin_amdgcn_mfma_f32_16x16x32_f16(ah[icq2], bl, accl[nf], 0, 0, 0);
                }
            }
            __syncthreads();
        }
    }

    int pxo = p0 + wave * 16 + g * 4;
#pragma unroll
    for (int nf = 0; nf < 8; nf++) {
        int oc = nf * 16 + row;
        float sc = bn_g[oc] * rsqrtf(bn_v[oc] + EPS);
        float sh = bn_b[oc] - bn_m[oc] * sc;
        float bi = bias[oc];
#pragma unroll
        for (int r = 0; r < 4; r++) {
            float v = acch[nf][r] + accl[nf][r] * ILOSC + bi;
            v = fmaxf(v * sc + sh, 0.f);
            if (NHWC_OUT)
                out[((size_t)b * HW + pxo + r) * C + oc] = v;
            else
                out[((size_t)b * C + oc) * HW + pxo + r] = v;
        }
    }
}

// ---------------- per-(b,c) max & mean reduce (NCHW input) -----------------
__global__ __launch_bounds__(256) void reduce_bc(
    const float* __restrict__ o2, float* __restrict__ mx, float* __restrict__ av)
{
    int bc = blockIdx.x;
    const float* p = o2 + (size_t)bc * HW;
    int t = threadIdx.x;
    float m = -INFINITY, s = 0.f;
    for (int i = t; i < HW; i += 256) {
        float v = p[i];
        m = fmaxf(m, v);
        s += v;
    }
    __shared__ float sm[256], ss[256];
    sm[t] = m; ss[t] = s;
    __syncthreads();
    for (int off = 128; off > 0; off >>= 1) {
        if (t < off) {
            sm[t] = fmaxf(sm[t], sm[t + off]);
            ss[t] += ss[t + off];
        }
        __syncthreads();
    }
    if (t == 0) {
        mx[bc] = sm[0];
        av[bc] = ss[0] / (float)HW;
    }
}

// ---------------- channel attention MLP + sigmoid --------------------------
__global__ __launch_bounds__(128) void cam_gate(
    const float* __restrict__ mx, const float* __restrict__ av,
    const float* __restrict__ w1, const float* __restrict__ w2,
    float* __restrict__ ch)
{
    int b = blockIdx.x;
    int t = threadIdx.x;
    __shared__ float smx[C], sav[C], h1[32], h2[32];
    smx[t] = mx[b * C + t];
    sav[t] = av[b * C + t];
    __syncthreads();
    if (t < 32) {
        float a = 0.f, c = 0.f;
        for (int i = 0; i < C; i++) {
            float w = w1[t * C + i];
            a = fmaf(smx[i], w, a);
            c = fmaf(sav[i], w, c);
        }
        h1[t] = fmaxf(a, 0.f);
        h2[t] = fmaxf(c, 0.f);
    }
    __syncthreads();
    float a = 0.f;
#pragma unroll
    for (int j = 0; j < 32; j++) a += (h1[j] + h2[j]) * w2[t * 32 + j];
    ch[b * C + t] = 1.f / (1.f + __expf(-a));
}

// ---------------- final gating scale (in-place on out) ---------------------
__global__ __launch_bounds__(256) void scale_out(
    float* __restrict__ o2, const float* __restrict__ ch)
{
    int e = blockIdx.x * 256 + threadIdx.x;
    if (e >= B * C * HW / 4) return;
    int bc = e / (HW / 4);
    float g = ch[bc];
    float4 v = reinterpret_cast<const float4*>(o2)[e];
    v.x *= g; v.y *= g; v.z *= g; v.w *= g;
    reinterpret_cast<float4*>(o2)[e] = v;
}

extern "C" void kernel_launch(void* const* d_in, const int* in_sizes, int n_in,
                              void* d_out, int out_size, void* d_ws, size_t ws_size,
                              hipStream_t stream) {
    const float* x      = (const float*)d_in[0];
    const float* off_w1 = (const float*)d_in[1];
    const float* off_b1 = (const float*)d_in[2];
    const float* dcn_w1 = (const float*)d_in[3];
    const float* dcn_b1 = (const float*)d_in[4];
    const float* bn_g1  = (const float*)d_in[5];
    const float* bn_b1  = (const float*)d_in[6];
    const float* bn_m1  = (const float*)d_in[7];
    const float* bn_v1  = (const float*)d_in[8];
    const float* off_w2 = (const float*)d_in[9];
    const float* off_b2 = (const float*)d_in[10];
    const float* dcn_w2 = (const float*)d_in[11];
    const float* dcn_b2 = (const float*)d_in[12];
    const float* bn_g2  = (const float*)d_in[13];
    const float* bn_b2  = (const float*)d_in[14];
    const float* bn_m2  = (const float*)d_in[15];
    const float* bn_v2  = (const float*)d_in[16];
    const float* cam_w1 = (const float*)d_in[17];
    const float* cam_w2 = (const float*)d_in[18];
    float* out = (float*)d_out;

    float* ws  = (float*)d_ws;
    float* xt  = ws;                      // 9,437,184 f32 (NHWC x)
    float* o1t = xt + 9437184;            // 9,437,184 f32 (NHWC o1)
    float* omt = o1t + 9437184;           // 2,359,296 f32 (b,p,32)
    _Float16* wt1h = (_Float16*)(omt + 2359296);  // 147,456 f16 each
    _Float16* wt1l = wt1h + 147456;
    _Float16* wt2h = wt1l + 147456;
    _Float16* wt2l = wt2h + 147456;
    _Float16* ow1h = wt2l + 147456;               // 36,864 f16 each
    _Float16* ow1l = ow1h + 36864;
    _Float16* ow2h = ow1l + 36864;
    _Float16* ow2l = ow2h + 36864;
    float* mxv = (float*)(ow2l + 36864);
    float* avv = mxv + 1024;
    float* chv = avv + 1024;

    nchw_to_nhwc<<<B * 288 * 4, 256, 0, stream>>>(x, xt);
    wt_split <<<576, 256, 0, stream>>>(dcn_w1, wt1h, wt1l);
    wt_split <<<576, 256, 0, stream>>>(dcn_w2, wt2h, wt2l);
    offw_split<<<144, 256, 0, stream>>>(off_w1, ow1h, ow1l);
    offw_split<<<144, 256, 0, stream>>>(off_w2, ow2h, ow2l);

    // stage 1: x(NHWC) -> o1t(NHWC)
    off_mfma<<<1152, 256, 0, stream>>>(xt, ow1h, ow1l, off_b1, omt);
    dcn_mfma<true><<<1152, 256, 0, stream>>>(xt, omt, wt1h, wt1l, dcn_b1,
                                             bn_g1, bn_b1, bn_m1, bn_v1, o1t);
    // stage 2: o1t(NHWC) -> out(NCHW, in d_out)
    off_mfma<<<1152, 256, 0, stream>>>(o1t, ow2h, ow2l, off_b2, omt);
    dcn_mfma<false><<<1152, 256, 0, stream>>>(o1t, omt, wt2h, wt2l, dcn_b2,
                                              bn_g2, bn_b2, bn_m2, bn_v2, out);

    // channel attention on out (NCHW), gate in-place
    reduce_bc<<<B * C, 256, 0, stream>>>(out, mxv, avv);
    cam_gate <<<B, 128, 0, stream>>>(mxv, avv, cam_w1, cam_w2, chv);
    scale_out<<<(B * C * HW / 4 + 255) / 256, 256, 0, stream>>>(out, chv);
}